// Round 3
// baseline (100.466 us; speedup 1.0000x reference)
//
#include <hip/hip_runtime.h>
#include <hip/hip_bf16.h>

// Problem constants
constexpr int B = 8, N = 2048, J = 4, F = 16, C = 2;

typedef float fx4 __attribute__((ext_vector_type(4)));   // native vector for nontemporal builtins

// ---------------- kernel 1: t[b][m][c*4+j] = sum_f cw[c,j*F+f] * x[b,f,m] ----
__global__ __launch_bounds__(256) void gnn_prep_kernel(
    const float* __restrict__ x,    // [B,F,N]
    const float* __restrict__ cw,   // [C, J*F]
    float* __restrict__ t_ws)       // [B,N,8]
{
    __shared__ float s_cw[C * J * F];   // 128 floats
    const int tid = threadIdx.x;
    if (tid < C * J * F) s_cw[tid] = cw[tid];
    __syncthreads();

    const int gid = blockIdx.x * 256 + tid;   // B*N threads total
    const int b = gid >> 11;                  // /N
    const int m = gid & (N - 1);

    const float* xb = x + (size_t)b * F * N + m;
    float xv[F];
#pragma unroll
    for (int f = 0; f < F; ++f) xv[f] = xb[(size_t)f * N];

    float t8[8];
#pragma unroll
    for (int c = 0; c < C; ++c) {
#pragma unroll
        for (int j = 0; j < J; ++j) {
            float s = 0.f;
#pragma unroll
            for (int f = 0; f < F; ++f) s += s_cw[c * (J * F) + j * F + f] * xv[f];
            t8[c * 4 + j] = s;
        }
    }
    float4* dst = (float4*)(t_ws + (size_t)gid * 8);
    dst[0] = *(float4*)&t8[0];
    dst[1] = *(float4*)&t8[4];
}

// ---------------- kernel 2: out[b,n,c] = sum_m sum_j W[b,m,n,j]*t[b,m,c4j] + cb[c]
constexpr int TN = 32;            // n-columns per block
constexpr int NT = N / TN;        // 64 n-tiles per b
constexpr int BT = 512;           // threads per block
constexpr int MSUB = 16;          // m-splits inside block
constexpr int MC = N / MSUB;      // 128 m per split

__global__ __launch_bounds__(512) void gnn_main_kernel(
    const float* __restrict__ W,    // [B,N,N,J]
    const float* __restrict__ t_ws, // [B,N,8]
    const float* __restrict__ cb,   // [C]
    float* __restrict__ out)        // [B,N,C]
{
    __shared__ float tl[N * 8];              // 64 KB
    __shared__ float red[MSUB][TN][C];       // 4 KB

    const int tid = threadIdx.x;
    const int blk = blockIdx.x;              // b*NT + ntile
    const int b = blk >> 6;                  // /NT
    const int ntile = blk & (NT - 1);
    const int n0 = ntile * TN;

    // stage t[b] into LDS, coalesced float4
    {
        const float4* src = (const float4*)(t_ws + (size_t)b * N * 8);
        float4* dst = (float4*)tl;
#pragma unroll
        for (int i = 0; i < (N * 8 / 4) / BT; ++i)
            dst[i * BT + tid] = src[i * BT + tid];
    }
    __syncthreads();

    const int nl = tid & (TN - 1);
    const int msub = tid >> 5;               // tid / TN
    const int m0 = msub * MC;

    const fx4* Wp = (const fx4*)W + (((size_t)b * N + m0) * N + n0 + nl);

    float acc0 = 0.f, acc1 = 0.f;
#pragma unroll 8
    for (int mi = 0; mi < MC; ++mi) {
        fx4 w4 = __builtin_nontemporal_load(Wp + (size_t)mi * N);
        const float4* tv = (const float4*)&tl[(m0 + mi) * 8];
        float4 t0 = tv[0];   // c=0, j=0..3  (broadcast within half-wave: free)
        float4 t1 = tv[1];   // c=1
        acc0 += w4.x * t0.x + w4.y * t0.y + w4.z * t0.z + w4.w * t0.w;
        acc1 += w4.x * t1.x + w4.y * t1.y + w4.z * t1.z + w4.w * t1.w;
    }

    red[msub][nl][0] = acc0;
    red[msub][nl][1] = acc1;
    __syncthreads();

    // combine 16 partials, write coalesced: tid -> (n, c), c fastest
    if (tid < TN * C) {
        const int nl2 = tid >> 1;
        const int c = tid & 1;
        float s = cb[c];
#pragma unroll
        for (int k = 0; k < MSUB; ++k) s += red[k][nl2][c];
        out[((size_t)b * N + n0 + nl2) * C + c] = s;
    }
}

extern "C" void kernel_launch(void* const* d_in, const int* in_sizes, int n_in,
                              void* d_out, int out_size, void* d_ws, size_t ws_size,
                              hipStream_t stream) {
    const float* W  = (const float*)d_in[0];
    const float* x  = (const float*)d_in[1];
    const float* cw = (const float*)d_in[2];
    const float* cb = (const float*)d_in[3];
    float* out  = (float*)d_out;
    float* t_ws = (float*)d_ws;   // B*N*8 floats = 512 KB

    gnn_prep_kernel<<<dim3(B * N / 256), dim3(256), 0, stream>>>(x, cw, t_ws);
    gnn_main_kernel<<<dim3(B * NT), dim3(BT), 0, stream>>>(W, t_ws, cb, out);
}

// Round 4
// 97.951 us; speedup vs baseline: 1.0257x; 1.0257x over previous
//
#include <hip/hip_runtime.h>
#include <hip/hip_bf16.h>

// Problem constants
constexpr int B = 8, N = 2048, J = 4, F = 16, C = 2;
constexpr int MCH = 64;          // m-chunks per b (reduction split)
constexpr int MR  = N / MCH;     // 32 m-rows per chunk (1 MB sequential read)

typedef float fx4 __attribute__((ext_vector_type(4)));

// ---- kernel 1: t[b][m][c*4+j] = sum_f cw[c,j*F+f] * x[b,f,m] ----
__global__ __launch_bounds__(256) void gnn_prep_kernel(
    const float* __restrict__ x,    // [B,F,N]
    const float* __restrict__ cw,   // [C, J*F]
    float* __restrict__ t_ws)       // [B,N,8]
{
    __shared__ float s_cw[C * J * F];
    const int tid = threadIdx.x;
    if (tid < C * J * F) s_cw[tid] = cw[tid];
    __syncthreads();

    const int gid = blockIdx.x * 256 + tid;   // B*N threads
    const int b = gid >> 11;
    const int m = gid & (N - 1);

    const float* xb = x + (size_t)b * F * N + m;
    float xv[F];
#pragma unroll
    for (int f = 0; f < F; ++f) xv[f] = xb[(size_t)f * N];

    float t8[8];
#pragma unroll
    for (int c = 0; c < C; ++c) {
#pragma unroll
        for (int j = 0; j < J; ++j) {
            float s = 0.f;
#pragma unroll
            for (int f = 0; f < F; ++f) s += s_cw[c * (J * F) + j * F + f] * xv[f];
            t8[c * 4 + j] = s;
        }
    }
    float4* dst = (float4*)(t_ws + (size_t)gid * 8);
    dst[0] = *(float4*)&t8[0];
    dst[1] = *(float4*)&t8[4];
}

// ---- kernel 2: sequential-stream main loop ----
// block = (b, mc): reads W rows m0..m0+MR-1 (1 MB contiguous), accumulates
// partial[n][c] over its m-chunk for ALL n, writes part[blk][c][n].
__global__ __launch_bounds__(512) void gnn_main_kernel(
    const float* __restrict__ W,    // [B,N,N,J]
    const float* __restrict__ t_ws, // [B,N,8]
    float* __restrict__ part)       // [B*MCH][C][N]
{
    __shared__ float tl[MR * 8];    // 1 KB

    const int tid = threadIdx.x;
    const int blk = blockIdx.x;     // b*MCH + mc
    const int mc = blk & (MCH - 1);
    const int b  = blk / MCH;
    const int m0 = mc * MR;

    if (tid < MR * 8) tl[tid] = t_ws[((size_t)b * N + m0) * 8 + tid];
    __syncthreads();

    const fx4* Wp = (const fx4*)W + ((size_t)b * N + m0) * N;  // one float4 == one n (J=4)

    float acc[4][2] = {};
#pragma unroll 2
    for (int r = 0; r < MR; ++r) {
        const fx4* row = Wp + (size_t)r * N;
        const float4 t0 = *(const float4*)&tl[r * 8];      // LDS broadcast (uniform)
        const float4 t1 = *(const float4*)&tl[r * 8 + 4];
#pragma unroll
        for (int k = 0; k < 4; ++k) {
            fx4 w4 = __builtin_nontemporal_load(row + k * 512 + tid);  // wave: 1 KB contiguous
            acc[k][0] += w4.x * t0.x + w4.y * t0.y + w4.z * t0.z + w4.w * t0.w;
            acc[k][1] += w4.x * t1.x + w4.y * t1.y + w4.z * t1.z + w4.w * t1.w;
        }
    }

    float* pb = part + (size_t)blk * C * N;
#pragma unroll
    for (int k = 0; k < 4; ++k) {
        const int n = k * 512 + tid;
        pb[n]     = acc[k][0];   // coalesced
        pb[N + n] = acc[k][1];
    }
}

// ---- kernel 3: reduce partials + bias, write out[b,n,c] ----
__global__ __launch_bounds__(256) void gnn_reduce_kernel(
    const float* __restrict__ part, // [B*MCH][C][N]
    const float* __restrict__ cb,   // [C]
    float* __restrict__ out)        // [B,N,C]
{
    const int gid = blockIdx.x * 256 + threadIdx.x;  // B*N
    const int b = gid >> 11;
    const int n = gid & (N - 1);

    float s0 = cb[0], s1 = cb[1];
    const float* pb = part + (size_t)b * MCH * C * N + n;
#pragma unroll 8
    for (int mcc = 0; mcc < MCH; ++mcc) {
        s0 += pb[(size_t)(mcc * C + 0) * N];   // coalesced across threads
        s1 += pb[(size_t)(mcc * C + 1) * N];
    }
    float2 o; o.x = s0; o.y = s1;
    *(float2*)&out[(size_t)gid * C] = o;
}

extern "C" void kernel_launch(void* const* d_in, const int* in_sizes, int n_in,
                              void* d_out, int out_size, void* d_ws, size_t ws_size,
                              hipStream_t stream) {
    const float* W  = (const float*)d_in[0];
    const float* x  = (const float*)d_in[1];
    const float* cw = (const float*)d_in[2];
    const float* cb = (const float*)d_in[3];
    float* out  = (float*)d_out;
    float* t_ws = (float*)d_ws;                       // B*N*8 floats = 512 KB
    float* part = t_ws + (size_t)B * N * 8;           // B*MCH*C*N floats = 8 MB

    gnn_prep_kernel<<<dim3(B * N / 256), dim3(256), 0, stream>>>(x, cw, t_ws);
    gnn_main_kernel<<<dim3(B * MCH), dim3(512), 0, stream>>>(W, t_ws, part);
    gnn_reduce_kernel<<<dim3(B * N / 256), dim3(256), 0, stream>>>(part, cb, out);
}

// Round 5
// 93.032 us; speedup vs baseline: 1.0799x; 1.0529x over previous
//
#include <hip/hip_runtime.h>
#include <hip/hip_bf16.h>

// Problem constants
constexpr int B = 8, N = 2048, J = 4, F = 16, C = 2;
constexpr int MCH = 64;          // m-chunks per b (reduction split)
constexpr int MR  = N / MCH;     // 32 m-rows per chunk (1 MB sequential W read)

typedef float fx4 __attribute__((ext_vector_type(4)));

// ---- main kernel: fused t-prep + W stream ----
// block = (b, mc): computes t[m0..m0+MR) in LDS, then reads W rows
// m0..m0+MR-1 (1 MB contiguous), accumulates partial[n][c] for ALL n,
// writes part[blk][c][n].
__global__ __launch_bounds__(512) void gnn_main_kernel(
    const float* __restrict__ W,    // [B,N,N,J]
    const float* __restrict__ x,    // [B,F,N]
    const float* __restrict__ cw,   // [C, J*F]
    float* __restrict__ part)       // [B*MCH][C][N]
{
    __shared__ float s_cw[C * J * F];   // 128 floats
    __shared__ float tl[MR * 8];        // 1 KB: [m_local][c*4+j]

    const int tid = threadIdx.x;
    const int blk = blockIdx.x;     // b*MCH + mc
    const int mc = blk & (MCH - 1);
    const int b  = blk / MCH;
    const int m0 = mc * MR;

    if (tid < C * J * F) s_cw[tid] = cw[tid];
    __syncthreads();

    // prologue: t[ml][c*4+j] = sum_f cw[c,j*F+f] * x[b,f,m0+ml]
    if (tid < MR * 8) {
        const int ml = tid >> 3;
        const int q  = tid & 7;          // c*4+j
        const int c  = q >> 2;
        const int j  = q & 3;
        const float* xb = x + (size_t)b * F * N + m0 + ml;
        float s = 0.f;
#pragma unroll
        for (int f = 0; f < F; ++f)
            s += s_cw[c * (J * F) + j * F + f] * xb[(size_t)f * N];
        tl[tid] = s;
    }
    __syncthreads();

    const fx4* Wp = (const fx4*)W + ((size_t)b * N + m0) * N;  // one fx4 == one n (J=4)

    float acc[4][2] = {};
#pragma unroll 2
    for (int r = 0; r < MR; ++r) {
        const fx4* row = Wp + (size_t)r * N;
        const float4 t0 = *(const float4*)&tl[r * 8];      // uniform LDS broadcast
        const float4 t1 = *(const float4*)&tl[r * 8 + 4];
#pragma unroll
        for (int k = 0; k < 4; ++k) {
            fx4 w4 = __builtin_nontemporal_load(row + k * 512 + tid);  // wave: 1 KB contiguous
            acc[k][0] += w4.x * t0.x + w4.y * t0.y + w4.z * t0.z + w4.w * t0.w;
            acc[k][1] += w4.x * t1.x + w4.y * t1.y + w4.z * t1.z + w4.w * t1.w;
        }
    }

    float* pb = part + (size_t)blk * C * N;
#pragma unroll
    for (int k = 0; k < 4; ++k) {
        const int n = k * 512 + tid;
        pb[n]     = acc[k][0];   // coalesced
        pb[N + n] = acc[k][1];
    }
}

// ---- reduce kernel: sum partials + bias, write out[b,n,c] ----
__global__ __launch_bounds__(256) void gnn_reduce_kernel(
    const float* __restrict__ part, // [B*MCH][C][N]
    const float* __restrict__ cb,   // [C]
    float* __restrict__ out)        // [B,N,C]
{
    const int gid = blockIdx.x * 256 + threadIdx.x;  // B*N
    const int b = gid >> 11;
    const int n = gid & (N - 1);

    float s0 = cb[0], s1 = cb[1];
    const float* pb = part + (size_t)b * MCH * C * N + n;
#pragma unroll 8
    for (int mcc = 0; mcc < MCH; ++mcc) {
        s0 += pb[(size_t)(mcc * C + 0) * N];   // coalesced across threads
        s1 += pb[(size_t)(mcc * C + 1) * N];
    }
    float2 o; o.x = s0; o.y = s1;
    *(float2*)&out[(size_t)gid * C] = o;
}

extern "C" void kernel_launch(void* const* d_in, const int* in_sizes, int n_in,
                              void* d_out, int out_size, void* d_ws, size_t ws_size,
                              hipStream_t stream) {
    const float* W  = (const float*)d_in[0];
    const float* x  = (const float*)d_in[1];
    const float* cw = (const float*)d_in[2];
    const float* cb = (const float*)d_in[3];
    float* out  = (float*)d_out;
    float* part = (float*)d_ws;   // B*MCH*C*N floats = 8 MB

    gnn_main_kernel<<<dim3(B * MCH), dim3(512), 0, stream>>>(W, x, cw, part);
    gnn_reduce_kernel<<<dim3(B * N / 256), dim3(256), 0, stream>>>(part, cb, out);
}

// Round 6
// 89.338 us; speedup vs baseline: 1.1246x; 1.0414x over previous
//
#include <hip/hip_runtime.h>
#include <hip/hip_bf16.h>

// Problem constants
constexpr int B = 8, N = 2048, J = 4, F = 16, C = 2;
constexpr int MCH = 32;          // m-chunks per b (reduction split)
constexpr int MR  = N / MCH;     // 64 m-rows per chunk
constexpr int NH  = 2;           // n-halves per block row-range
constexpr int HN  = N / NH;      // 1024 n per half

typedef float fx4 __attribute__((ext_vector_type(4)));

// ---- main kernel: fused t-prep + W stream ----
// block = (b, mc, nh): computes t[m0..m0+MR) in LDS, streams
// W[b, m0..m0+MR, nh*HN..(nh+1)*HN, :] (64 x 16KB sequential runs),
// writes part[b][nh][mc][c][HN].
__global__ __launch_bounds__(512) void gnn_main_kernel(
    const float* __restrict__ W,    // [B,N,N,J]
    const float* __restrict__ x,    // [B,F,N]
    const float* __restrict__ cw,   // [C, J*F]
    float* __restrict__ part)       // [B][NH][MCH][C][HN]
{
    __shared__ float s_cw[C * J * F];   // 128 floats
    __shared__ float tl[MR * 8];        // 2 KB: [m_local][c*4+j]

    const int tid = threadIdx.x;
    const int blk = blockIdx.x;          // b*64 + mc*2 + nh
    const int b  = blk >> 6;
    const int r6 = blk & 63;
    const int mc = r6 >> 1;
    const int nh = r6 & 1;
    const int m0 = mc * MR;
    const int n0 = nh * HN;

    if (tid < C * J * F) s_cw[tid] = cw[tid];
    __syncthreads();

    // prologue: t[ml][c*4+j] = sum_f cw[c,j*F+f] * x[b,f,m0+ml]   (512 threads == MR*8)
    {
        const int ml = tid >> 3;
        const int q  = tid & 7;          // c*4+j
        const int c  = q >> 2;
        const int j  = q & 3;
        const float* xb = x + (size_t)b * F * N + m0 + ml;
        float s = 0.f;
#pragma unroll
        for (int f = 0; f < F; ++f)
            s += s_cw[c * (J * F) + j * F + f] * xb[(size_t)f * N];
        tl[tid] = s;
    }
    __syncthreads();

    const fx4* Wp = (const fx4*)W + ((size_t)b * N + m0) * N + n0;  // one fx4 == one n (J=4)

    float acc[2][2] = {};   // [k][c]
#pragma unroll 4
    for (int r = 0; r < MR; ++r) {
        const fx4* row = Wp + (size_t)r * N;
        const float4 t0 = *(const float4*)&tl[r * 8];      // uniform LDS broadcast
        const float4 t1 = *(const float4*)&tl[r * 8 + 4];
#pragma unroll
        for (int k = 0; k < 2; ++k) {
            fx4 w4 = __builtin_nontemporal_load(row + k * 512 + tid);  // wave: 1 KB contiguous
            acc[k][0] += w4.x * t0.x + w4.y * t0.y + w4.z * t0.z + w4.w * t0.w;
            acc[k][1] += w4.x * t1.x + w4.y * t1.y + w4.z * t1.z + w4.w * t1.w;
        }
    }

    float* pb = part + ((size_t)((b * NH + nh) * MCH + mc) * C) * HN;
#pragma unroll
    for (int k = 0; k < 2; ++k) {
        const int n = k * 512 + tid;
        pb[n]      = acc[k][0];   // coalesced
        pb[HN + n] = acc[k][1];
    }
}

// ---- reduce kernel: sum partials + bias, write out[b,n,c] ----
__global__ __launch_bounds__(256) void gnn_reduce_kernel(
    const float* __restrict__ part, // [B][NH][MCH][C][HN]
    const float* __restrict__ cb,   // [C]
    float* __restrict__ out)        // [B,N,C]
{
    const int gid = blockIdx.x * 256 + threadIdx.x;  // B*N
    const int b  = gid >> 11;
    const int n  = gid & (N - 1);
    const int nh = n >> 10;
    const int nl = n & (HN - 1);

    float s0 = cb[0], s1 = cb[1];
    const float* pb = part + ((size_t)(b * NH + nh) * MCH * C) * HN + nl;
#pragma unroll 8
    for (int mc = 0; mc < MCH; ++mc) {
        s0 += pb[(size_t)mc * (C * HN)];        // coalesced across threads
        s1 += pb[(size_t)mc * (C * HN) + HN];
    }
    float2 o; o.x = s0; o.y = s1;
    *(float2*)&out[(size_t)gid * C] = o;
}

extern "C" void kernel_launch(void* const* d_in, const int* in_sizes, int n_in,
                              void* d_out, int out_size, void* d_ws, size_t ws_size,
                              hipStream_t stream) {
    const float* W  = (const float*)d_in[0];
    const float* x  = (const float*)d_in[1];
    const float* cw = (const float*)d_in[2];
    const float* cb = (const float*)d_in[3];
    float* out  = (float*)d_out;
    float* part = (float*)d_ws;   // B*NH*MCH*C*HN floats = 4 MB

    gnn_main_kernel<<<dim3(B * MCH * NH), dim3(512), 0, stream>>>(W, x, cw, part);
    gnn_reduce_kernel<<<dim3(B * N / 256), dim3(256), 0, stream>>>(part, cb, out);
}